// Round 3
// baseline (578.458 us; speedup 1.0000x reference)
//
#include <hip/hip_runtime.h>
#include <hip/hip_bf16.h>
#include <stdint.h>

typedef __bf16 bf16;
typedef __bf16 bf16x4 __attribute__((ext_vector_type(4)));
typedef __bf16 bf16x8 __attribute__((ext_vector_type(8)));
typedef float f32x4 __attribute__((ext_vector_type(4)));
typedef float f32x16 __attribute__((ext_vector_type(16)));

#define N_HEADS 16
#define HEAD_DIM 128
#define SEQ 2048
#define DIM 2048
#define BATCH 2
#define MROWS (BATCH * SEQ)          // 4096
#define NQKV (3 * DIM)               // 6144
#define SM_SCALE 0.08838834764831845f  // 1/sqrt(128)
#define SMAX 24.0f                     // static softmax max

__device__ __forceinline__ bf16 f2b(float f) {
  union { __hip_bfloat16 h; bf16 b; } u;
  u.h = __float2bfloat16(f);
  return u.b;
}

// async global->LDS, 16B per lane. LDS dest is WAVE-UNIFORM base; HW writes
// lane i at base + i*16 (m104 semantics).
__device__ __forceinline__ void async16(const bf16* g, bf16* l) {
  __builtin_amdgcn_global_load_lds(
      (__attribute__((address_space(1))) void*)(uintptr_t)g,
      (__attribute__((address_space(3))) void*)(uintptr_t)l,
      16, 0, 0);
}

// ---------------------------------------------------------------- cvt f32->bf16
__global__ __launch_bounds__(256) void cvt_kernel(const float* __restrict__ src,
                                                  bf16* __restrict__ dst, int n) {
  int i = (blockIdx.x * 256 + threadIdx.x) * 8;
  if (i >= n) return;
  float4 a = *(const float4*)(src + i);
  float4 b = *(const float4*)(src + i + 4);
  bf16x8 o;
  o[0] = f2b(a.x); o[1] = f2b(a.y); o[2] = f2b(a.z); o[3] = f2b(a.w);
  o[4] = f2b(b.x); o[5] = f2b(b.y); o[6] = f2b(b.z); o[7] = f2b(b.w);
  *(bf16x8*)(dst + i) = o;
}

// ------------------------------------------------- m97-style 128x128x32 mainloop
__device__ __forceinline__ void gemm_tile_mainloop(
    const bf16* __restrict__ A, const bf16* __restrict__ Bw, int K,
    int rowBase, int colBase, bf16* lA, bf16* lB, f32x4 acc[4][4]) {
  const int t = threadIdx.x;
  const int w = t >> 6, lane = t & 63;
  const int lm = lane & 15, quad = lane >> 4;
  const int wr = (w >> 1) * 64, wc = (w & 1) * 64;

  for (int kt = 0; kt < K; kt += 32) {
#pragma unroll
    for (int i = 0; i < 2; i++) {
      const int c = i * 256 + t;
      const int r = c >> 2, cc = (c & 3) << 3;
      async16(A + (size_t)(rowBase + r) * K + (kt + cc), lA + (i * 256 + w * 64) * 8);
      async16(Bw + (size_t)(colBase + r) * K + (kt + cc), lB + (i * 256 + w * 64) * 8);
    }
    asm volatile("s_waitcnt vmcnt(0)" ::: "memory");
    __syncthreads();
    bf16x8 af[4], bfr[4];
#pragma unroll
    for (int f = 0; f < 4; f++)
      af[f] = *(const bf16x8*)(lA + (wr + f * 16 + lm) * 32 + quad * 8);
#pragma unroll
    for (int f = 0; f < 4; f++)
      bfr[f] = *(const bf16x8*)(lB + (wc + f * 16 + lm) * 32 + quad * 8);
#pragma unroll
    for (int fr = 0; fr < 4; fr++)
#pragma unroll
      for (int fc = 0; fc < 4; fc++)
        acc[fr][fc] = __builtin_amdgcn_mfma_f32_16x16x32_bf16(af[fr], bfr[fc], acc[fr][fc], 0, 0, 0);
    __syncthreads();
  }
}

// QKV projection: Q,K -> [B,H,S,Dh]; V -> TRANSPOSED [B,H,Dh,S]
__global__ __launch_bounds__(256) void gemm_qkv(const bf16* __restrict__ X,
                                                const bf16* __restrict__ W,
                                                bf16* __restrict__ Q,
                                                bf16* __restrict__ Kv,
                                                bf16* __restrict__ VT) {
  __shared__ __align__(16) bf16 lA[128 * 32];
  __shared__ __align__(16) bf16 lB[128 * 32];
  f32x4 acc[4][4];
  f32x4 z = {0.f, 0.f, 0.f, 0.f};
#pragma unroll
  for (int i = 0; i < 4; i++)
#pragma unroll
    for (int j = 0; j < 4; j++) acc[i][j] = z;

  const int rowBase = blockIdx.y * 128, colBase = blockIdx.x * 128;
  gemm_tile_mainloop(X, W, DIM, rowBase, colBase, lA, lB, acc);

  const int t = threadIdx.x, w = t >> 6, lane = t & 63;
  const int lm = lane & 15, quad = lane >> 4;
  const int wr = (w >> 1) * 64, wc = (w & 1) * 64;
  const int which = colBase >> 11;  // 0=Q 1=K 2=V
  if (which < 2) {
    bf16* dst = which ? Kv : Q;
#pragma unroll
    for (int fr = 0; fr < 4; fr++)
#pragma unroll
      for (int fc = 0; fc < 4; fc++)
#pragma unroll
        for (int r = 0; r < 4; r++) {
          int m = rowBase + wr + fr * 16 + quad * 4 + r;
          int n = (colBase + wc + fc * 16 + lm) & 2047;
          int h = n >> 7, d = n & 127;
          int b = m >> 11, s = m & 2047;
          dst[(((size_t)(b * N_HEADS + h) * SEQ) + s) * HEAD_DIM + d] = f2b(acc[fr][fc][r]);
        }
  } else {
#pragma unroll
    for (int fr = 0; fr < 4; fr++)
#pragma unroll
      for (int fc = 0; fc < 4; fc++) {
        int n = (colBase + wc + fc * 16 + lm) & 2047;
        int h = n >> 7, d = n & 127;
        int m = rowBase + wr + fr * 16 + quad * 4;
        int b = m >> 11, s = m & 2047;
        bf16x4 pk;
#pragma unroll
        for (int r = 0; r < 4; r++) pk[r] = f2b(acc[fr][fc][r]);
        *(bf16x4*)&VT[((size_t)(b * N_HEADS + h) * HEAD_DIM + d) * SEQ + s] = pk;
      }
  }
}

// Output projection
__global__ __launch_bounds__(256) void gemm_out(const bf16* __restrict__ A,
                                                const bf16* __restrict__ W,
                                                float* __restrict__ out) {
  __shared__ __align__(16) bf16 lA[128 * 32];
  __shared__ __align__(16) bf16 lB[128 * 32];
  f32x4 acc[4][4];
  f32x4 z = {0.f, 0.f, 0.f, 0.f};
#pragma unroll
  for (int i = 0; i < 4; i++)
#pragma unroll
    for (int j = 0; j < 4; j++) acc[i][j] = z;

  const int rowBase = blockIdx.y * 128, colBase = blockIdx.x * 128;
  gemm_tile_mainloop(A, W, DIM, rowBase, colBase, lA, lB, acc);

  const int t = threadIdx.x, w = t >> 6, lane = t & 63;
  const int lm = lane & 15, quad = lane >> 4;
  const int wr = (w >> 1) * 64, wc = (w & 1) * 64;
#pragma unroll
  for (int fr = 0; fr < 4; fr++)
#pragma unroll
    for (int fc = 0; fc < 4; fc++)
#pragma unroll
      for (int r = 0; r < 4; r++) {
        int m = rowBase + wr + fr * 16 + quad * 4 + r;
        int n = colBase + wc + fc * 16 + lm;
        out[(size_t)m * DIM + n] = acc[fr][fc][r];
      }
}

// --------------------------------------------- RMSNorm + RoPE (in place on q,k)
__global__ __launch_bounds__(256) void norm_rope(bf16* __restrict__ Q,
                                                 bf16* __restrict__ K,
                                                 const float* __restrict__ rope,
                                                 const float* __restrict__ qw,
                                                 const float* __restrict__ kw) {
  const int t = threadIdx.x, w = t >> 6, lane = t & 63;
  const int rid = blockIdx.x * 4 + w;
  const int which = rid >> 16;          // 0 = q, 1 = k
  const int row = rid & 65535;          // (b*16+h)*2048 + s
  bf16* ptr = (which ? K : Q) + (size_t)row * HEAD_DIM;
  const float* nw = which ? kw : qw;
  const int s = row & (SEQ - 1);

  float x0 = (float)ptr[lane];
  float x1 = (float)ptr[lane + 64];
  float ss = x0 * x0 + x1 * x1;
#pragma unroll
  for (int off = 32; off; off >>= 1) ss += __shfl_xor(ss, off);
  float r = rsqrtf(ss * (1.f / 128.f) + 1e-6f);
  float x0n = x0 * r * nw[lane];
  float x1n = x1 * r * nw[lane + 64];
  float4 f = ((const float4*)rope)[s * 64 + lane];
  float y0 = f.x * x0n + f.y * x1n;
  float y1 = f.z * x0n + f.w * x1n;
  if (!which) { y0 *= SM_SCALE; y1 *= SM_SCALE; }
  ptr[lane] = f2b(y0);
  ptr[lane + 64] = f2b(y1);
}

// --------------------------------------------------------- flash attention v3
// grid (S/128, B*H); block 256 = 4 waves. wave w: qh = w>>1 (64 q-rows, 2 reg
// q-sets), kb = w&1 (32-row K-band of the 64-row tile). Each kf/bv LDS read
// feeds 2 MFMAs (register q-reuse); K/V staged via global_load_lds with the
// XOR-swizzle applied to the SOURCE address. Cross-wave (kb-pair) O merge via
// LDS at the end, once per block.
__global__ __launch_bounds__(256, 2) void attn_kernel(const bf16* __restrict__ Q,
                                                      const bf16* __restrict__ K,
                                                      const bf16* __restrict__ VT,
                                                      bf16* __restrict__ O) {
  __shared__ __align__(16) bf16 Ks[64 * 128];      // [kr][chunk ^ (kr&15)]
  __shared__ __align__(16) bf16 Vs[128 * 64];      // [d][chunk ^ (d&7)]
  __shared__ __align__(16) bf16 Ps[4][64 * 36];    // per-wave P [q 0..63][k 0..31], pad->36

  const int t = threadIdx.x, w = t >> 6, lane = t & 63;
  const int lq = lane & 31, h = lane >> 5;
  const int qh = w >> 1, kb = w & 1;
  const int qt = blockIdx.x, bh = blockIdx.y;

  // hoisted Q B-frags, 2 q-sets of 32 rows
  bf16x8 qf[2][8];
#pragma unroll
  for (int qs = 0; qs < 2; qs++) {
    const bf16* Qp = Q + ((size_t)bh * SEQ + qt * 128 + qh * 64 + qs * 32 + lq) * HEAD_DIM;
#pragma unroll
    for (int ks = 0; ks < 8; ks++)
      qf[qs][ks] = *(const bf16x8*)(Qp + ks * 16 + h * 8);
  }

  f32x16 oacc[2][4];
#pragma unroll
  for (int qs = 0; qs < 2; qs++)
#pragma unroll
    for (int nb = 0; nb < 4; nb++)
#pragma unroll
      for (int e = 0; e < 16; e++) oacc[qs][nb][e] = 0.f;
  float rsum[2] = {0.f, 0.f};

  const bf16* kbase = K + (size_t)bh * SEQ * HEAD_DIM;
  const bf16* vbase = VT + (size_t)bh * HEAD_DIM * SEQ;
  bf16* myPs = Ps[w];
  const int kr = kb * 32 + lq;

  for (int j = 0; j < SEQ / 64; j++) {
    const bf16* kp = kbase + (size_t)j * 64 * HEAD_DIM;
    const bf16* vp = vbase + j * 64;
    // stage K [64][128]: LDS slot c -> global chunk (c&15) ^ ((c>>4)&15)
#pragma unroll
    for (int i = 0; i < 4; i++) {
      int c = i * 256 + t;
      int r = c >> 4, cc = c & 15;
      async16(kp + r * 128 + (((cc ^ (r & 15)) & 15) << 3), Ks + (i * 256 + w * 64) * 8);
    }
    // stage V^T [128][64]: LDS slot c -> global chunk (c&7) ^ ((c>>3)&7)
#pragma unroll
    for (int i = 0; i < 4; i++) {
      int c = i * 256 + t;
      int d = c >> 3, cc = c & 7;
      async16(vp + (size_t)d * SEQ + (((cc ^ (d & 7)) & 7) << 3), Vs + (i * 256 + w * 64) * 8);
    }
    asm volatile("s_waitcnt vmcnt(0)" ::: "memory");
    __syncthreads();

    // S^T = K Q^T on this wave's 32-row K-band; each kf feeds both q-sets
    f32x16 sacc[2];
#pragma unroll
    for (int qs = 0; qs < 2; qs++)
#pragma unroll
      for (int e = 0; e < 16; e++) sacc[qs][e] = -SMAX;
#pragma unroll
    for (int ks = 0; ks < 8; ks++) {
      int c = ks * 2 + h;
      bf16x8 kf = *(const bf16x8*)&Ks[kr * 128 + ((c ^ (kr & 15)) << 3)];
      sacc[0] = __builtin_amdgcn_mfma_f32_32x32x16_bf16(kf, qf[0][ks], sacc[0], 0, 0, 0);
      sacc[1] = __builtin_amdgcn_mfma_f32_32x32x16_bf16(kf, qf[1][ks], sacc[1], 0, 0, 0);
    }

    // exp + pack into per-wave Ps[q][k]  (k-local = g*8 + h*4 + e)
#pragma unroll
    for (int qs = 0; qs < 2; qs++)
#pragma unroll
      for (int g = 0; g < 4; g++) {
        bf16x4 pk;
#pragma unroll
        for (int e = 0; e < 4; e++) {
          float p = __expf(sacc[qs][g * 4 + e]);
          rsum[qs] += p;
          pk[e] = f2b(p);
        }
        *(bf16x4*)&myPs[(qs * 32 + lq) * 36 + g * 8 + h * 4] = pk;
      }

    // O += P V on this wave's K-band; each bv feeds both q-sets
#pragma unroll
    for (int ks2 = 0; ks2 < 2; ks2++) {
      bf16x8 ap0 = *(const bf16x8*)&myPs[lq * 36 + ks2 * 16 + h * 8];
      bf16x8 ap1 = *(const bf16x8*)&myPs[(32 + lq) * 36 + ks2 * 16 + h * 8];
      int c2 = kb * 4 + ks2 * 2 + h;
#pragma unroll
      for (int nb = 0; nb < 4; nb++) {
        int rv = nb * 32 + lq;
        bf16x8 bv = *(const bf16x8*)&Vs[rv * 64 + ((c2 ^ (rv & 7)) << 3)];
        oacc[0][nb] = __builtin_amdgcn_mfma_f32_32x32x16_bf16(ap0, bv, oacc[0][nb], 0, 0, 0);
        oacc[1][nb] = __builtin_amdgcn_mfma_f32_32x32x16_bf16(ap1, bv, oacc[1][nb], 0, 0, 0);
      }
    }
    __syncthreads();
  }

  // ---- epilogue: merge kb pairs via LDS (alias Ks/Vs), normalize, store
  rsum[0] += __shfl_xor(rsum[0], 32);
  rsum[1] += __shfl_xor(rsum[1], 32);
  float* Om = (float*)Ks;   // [pair][64 q][32 d] f32 = 16 KB
  float* Rs = (float*)Vs;   // [pair][qs][32] f32
  const int pair = qh;
  const int b = bh >> 4, hh = bh & 15;
  float inv[2] = {0.f, 0.f};

#pragma unroll
  for (int nb = 0; nb < 4; nb++) {
    if (kb == 1) {
      if (nb == 0 && h == 0) {
        Rs[(pair * 2 + 0) * 32 + lq] = rsum[0];
        Rs[(pair * 2 + 1) * 32 + lq] = rsum[1];
      }
#pragma unroll
      for (int qs = 0; qs < 2; qs++)
#pragma unroll
        for (int r = 0; r < 16; r++) {
          int rowm = (r & 3) + 8 * (r >> 2) + 4 * h;
          Om[(pair * 64 + qs * 32 + rowm) * 32 + lq] = oacc[qs][nb][r];
        }
    }
    __syncthreads();
    if (kb == 0) {
      if (nb == 0) {
        inv[0] = 1.f / (rsum[0] + Rs[(pair * 2 + 0) * 32 + lq]);
        inv[1] = 1.f / (rsum[1] + Rs[(pair * 2 + 1) * 32 + lq]);
      }
#pragma unroll
      for (int qs = 0; qs < 2; qs++)
#pragma unroll
        for (int r = 0; r < 16; r++) {
          int rowm = (r & 3) + 8 * (r >> 2) + 4 * h;
          float val = oacc[qs][nb][r] + Om[(pair * 64 + qs * 32 + rowm) * 32 + lq];
          float iv = __shfl(inv[qs], rowm);
          int qg = qt * 128 + qh * 64 + qs * 32 + rowm;
          O[((size_t)b * SEQ + qg) * DIM + hh * HEAD_DIM + nb * 32 + lq] = f2b(val * iv);
        }
    }
    __syncthreads();
  }
}

extern "C" void kernel_launch(void* const* d_in, const int* in_sizes, int n_in,
                              void* d_out, int out_size, void* d_ws, size_t ws_size,
                              hipStream_t stream) {
  const float* x    = (const float*)d_in[0];
  const float* rope = (const float*)d_in[1];
  const float* Wq   = (const float*)d_in[2];
  const float* Wk   = (const float*)d_in[3];
  const float* Wv   = (const float*)d_in[4];
  const float* Wo   = (const float*)d_in[5];
  const float* qw   = (const float*)d_in[6];
  const float* kw   = (const float*)d_in[7];
  float* out = (float*)d_out;

  char* ws = (char*)d_ws;
  bf16* xb   = (bf16*)ws;                        // 16 MB; reused as attn-out
  bf16* wqkv = (bf16*)(ws + (16u << 20));        // 24 MB
  bf16* wo   = (bf16*)(ws + (40u << 20));        // 8 MB
  bf16* qb   = (bf16*)(ws + (48u << 20));        // 16 MB [B,H,S,Dh]
  bf16* kb   = (bf16*)(ws + (64u << 20));        // 16 MB [B,H,S,Dh]
  bf16* vt   = (bf16*)(ws + (80u << 20));        // 16 MB [B,H,Dh,S]
  bf16* attn = xb;

  const int NX = MROWS * DIM;
  const int NW = DIM * DIM;

  cvt_kernel<<<NX / 8 / 256, 256, 0, stream>>>(x, xb, NX);
  cvt_kernel<<<NW / 8 / 256, 256, 0, stream>>>(Wq, wqkv, NW);
  cvt_kernel<<<NW / 8 / 256, 256, 0, stream>>>(Wk, wqkv + NW, NW);
  cvt_kernel<<<NW / 8 / 256, 256, 0, stream>>>(Wv, wqkv + 2 * (size_t)NW, NW);
  cvt_kernel<<<NW / 8 / 256, 256, 0, stream>>>(Wo, wo, NW);

  gemm_qkv<<<dim3(NQKV / 128, MROWS / 128), 256, 0, stream>>>(xb, wqkv, qb, kb, vt);
  norm_rope<<<(2 * BATCH * N_HEADS * SEQ) / 4, 256, 0, stream>>>(qb, kb, rope, qw, kw);
  attn_kernel<<<dim3(SEQ / 128, BATCH * N_HEADS), 256, 0, stream>>>(qb, kb, vt, attn);
  gemm_out<<<dim3(DIM / 128, MROWS / 128), 256, 0, stream>>>(attn, wo, out);
}

// Round 4
// 496.661 us; speedup vs baseline: 1.1647x; 1.1647x over previous
//
#include <hip/hip_runtime.h>
#include <hip/hip_bf16.h>
#include <stdint.h>

typedef __bf16 bf16;
typedef __bf16 bf16x4 __attribute__((ext_vector_type(4)));
typedef __bf16 bf16x8 __attribute__((ext_vector_type(8)));
typedef float f32x4 __attribute__((ext_vector_type(4)));
typedef float f32x16 __attribute__((ext_vector_type(16)));

#define N_HEADS 16
#define HEAD_DIM 128
#define SEQ 2048
#define DIM 2048
#define BATCH 2
#define MROWS (BATCH * SEQ)          // 4096
#define NQKV (3 * DIM)               // 6144
#define SM_SCALE 0.08838834764831845f  // 1/sqrt(128)
#define SMAX 24.0f                     // static softmax max

__device__ __forceinline__ bf16 f2b(float f) {
  union { __hip_bfloat16 h; bf16 b; } u;
  u.h = __float2bfloat16(f);
  return u.b;
}

__device__ __forceinline__ uint32_t pack2(float a, float b) {
  union { __hip_bfloat16 h; unsigned short s; } ua, ub;
  ua.h = __float2bfloat16(a); ub.h = __float2bfloat16(b);
  return (uint32_t)ua.s | ((uint32_t)ub.s << 16);   // a in low 16 (even k)
}

// async global->LDS, 16B per lane; LDS dest is wave-uniform base (m104).
__device__ __forceinline__ void async16(const bf16* g, bf16* l) {
  __builtin_amdgcn_global_load_lds(
      (__attribute__((address_space(1))) void*)(uintptr_t)g,
      (__attribute__((address_space(3))) void*)(uintptr_t)l,
      16, 0, 0);
}

// ---------------------------------------------------------------- cvt f32->bf16
__global__ __launch_bounds__(256) void cvt_kernel(const float* __restrict__ src,
                                                  bf16* __restrict__ dst, int n) {
  int i = (blockIdx.x * 256 + threadIdx.x) * 8;
  if (i >= n) return;
  float4 a = *(const float4*)(src + i);
  float4 b = *(const float4*)(src + i + 4);
  bf16x8 o;
  o[0] = f2b(a.x); o[1] = f2b(a.y); o[2] = f2b(a.z); o[3] = f2b(a.w);
  o[4] = f2b(b.x); o[5] = f2b(b.y); o[6] = f2b(b.z); o[7] = f2b(b.w);
  *(bf16x8*)(dst + i) = o;
}

// fused cvt of the 4 weight matrices (each DIM*DIM); w0..w2 -> wqkv, w3 -> wo
__global__ __launch_bounds__(256) void cvt_w4(const float* __restrict__ w0,
                                              const float* __restrict__ w1,
                                              const float* __restrict__ w2,
                                              const float* __restrict__ w3,
                                              bf16* __restrict__ wqkv,
                                              bf16* __restrict__ wo) {
  const int per = (DIM * DIM) / 8 / 256;     // blocks per matrix
  int which = blockIdx.x / per;
  int i = (blockIdx.x % per) * 256 * 8 + threadIdx.x * 8;
  const float* src = which == 0 ? w0 : which == 1 ? w1 : which == 2 ? w2 : w3;
  bf16* dst = which < 3 ? wqkv + (size_t)which * DIM * DIM : wo;
  float4 a = *(const float4*)(src + i);
  float4 b = *(const float4*)(src + i + 4);
  bf16x8 o;
  o[0] = f2b(a.x); o[1] = f2b(a.y); o[2] = f2b(a.z); o[3] = f2b(a.w);
  o[4] = f2b(b.x); o[5] = f2b(b.y); o[6] = f2b(b.z); o[7] = f2b(b.w);
  *(bf16x8*)(dst + i) = o;
}

// ------------------------------------------------- m97-style 128x128x32 mainloop
__device__ __forceinline__ void gemm_tile_mainloop(
    const bf16* __restrict__ A, const bf16* __restrict__ Bw, int K,
    int rowBase, int colBase, bf16* lA, bf16* lB, f32x4 acc[4][4]) {
  const int t = threadIdx.x;
  const int w = t >> 6, lane = t & 63;
  const int lm = lane & 15, quad = lane >> 4;
  const int wr = (w >> 1) * 64, wc = (w & 1) * 64;

  for (int kt = 0; kt < K; kt += 32) {
#pragma unroll
    for (int i = 0; i < 2; i++) {
      const int c = i * 256 + t;
      const int r = c >> 2, cc = (c & 3) << 3;
      async16(A + (size_t)(rowBase + r) * K + (kt + cc), lA + (i * 256 + w * 64) * 8);
      async16(Bw + (size_t)(colBase + r) * K + (kt + cc), lB + (i * 256 + w * 64) * 8);
    }
    asm volatile("s_waitcnt vmcnt(0)" ::: "memory");
    __syncthreads();
    bf16x8 af[4], bfr[4];
#pragma unroll
    for (int f = 0; f < 4; f++)
      af[f] = *(const bf16x8*)(lA + (wr + f * 16 + lm) * 32 + quad * 8);
#pragma unroll
    for (int f = 0; f < 4; f++)
      bfr[f] = *(const bf16x8*)(lB + (wc + f * 16 + lm) * 32 + quad * 8);
#pragma unroll
    for (int fr = 0; fr < 4; fr++)
#pragma unroll
      for (int fc = 0; fc < 4; fc++)
        acc[fr][fc] = __builtin_amdgcn_mfma_f32_16x16x32_bf16(af[fr], bfr[fc], acc[fr][fc], 0, 0, 0);
    __syncthreads();
  }
}

// QKV projection: Q,K -> [B,H,S,Dh]; V -> TRANSPOSED [B,H,Dh,S]
__global__ __launch_bounds__(256) void gemm_qkv(const bf16* __restrict__ X,
                                                const bf16* __restrict__ W,
                                                bf16* __restrict__ Q,
                                                bf16* __restrict__ Kv,
                                                bf16* __restrict__ VT) {
  __shared__ __align__(16) bf16 lA[128 * 32];
  __shared__ __align__(16) bf16 lB[128 * 32];
  f32x4 acc[4][4];
  f32x4 z = {0.f, 0.f, 0.f, 0.f};
#pragma unroll
  for (int i = 0; i < 4; i++)
#pragma unroll
    for (int j = 0; j < 4; j++) acc[i][j] = z;

  const int rowBase = blockIdx.y * 128, colBase = blockIdx.x * 128;
  gemm_tile_mainloop(X, W, DIM, rowBase, colBase, lA, lB, acc);

  const int t = threadIdx.x, w = t >> 6, lane = t & 63;
  const int lm = lane & 15, quad = lane >> 4;
  const int wr = (w >> 1) * 64, wc = (w & 1) * 64;
  const int which = colBase >> 11;  // 0=Q 1=K 2=V
  if (which < 2) {
    bf16* dst = which ? Kv : Q;
#pragma unroll
    for (int fr = 0; fr < 4; fr++)
#pragma unroll
      for (int fc = 0; fc < 4; fc++)
#pragma unroll
        for (int r = 0; r < 4; r++) {
          int m = rowBase + wr + fr * 16 + quad * 4 + r;
          int n = (colBase + wc + fc * 16 + lm) & 2047;
          int h = n >> 7, d = n & 127;
          int b = m >> 11, s = m & 2047;
          dst[(((size_t)(b * N_HEADS + h) * SEQ) + s) * HEAD_DIM + d] = f2b(acc[fr][fc][r]);
        }
  } else {
#pragma unroll
    for (int fr = 0; fr < 4; fr++)
#pragma unroll
      for (int fc = 0; fc < 4; fc++) {
        int n = (colBase + wc + fc * 16 + lm) & 2047;
        int h = n >> 7, d = n & 127;
        int m = rowBase + wr + fr * 16 + quad * 4;
        int b = m >> 11, s = m & 2047;
        bf16x4 pk;
#pragma unroll
        for (int r = 0; r < 4; r++) pk[r] = f2b(acc[fr][fc][r]);
        *(bf16x4*)&VT[((size_t)(b * N_HEADS + h) * HEAD_DIM + d) * SEQ + s] = pk;
      }
  }
}

// Output projection
__global__ __launch_bounds__(256) void gemm_out(const bf16* __restrict__ A,
                                                const bf16* __restrict__ W,
                                                float* __restrict__ out) {
  __shared__ __align__(16) bf16 lA[128 * 32];
  __shared__ __align__(16) bf16 lB[128 * 32];
  f32x4 acc[4][4];
  f32x4 z = {0.f, 0.f, 0.f, 0.f};
#pragma unroll
  for (int i = 0; i < 4; i++)
#pragma unroll
    for (int j = 0; j < 4; j++) acc[i][j] = z;

  const int rowBase = blockIdx.y * 128, colBase = blockIdx.x * 128;
  gemm_tile_mainloop(A, W, DIM, rowBase, colBase, lA, lB, acc);

  const int t = threadIdx.x, w = t >> 6, lane = t & 63;
  const int lm = lane & 15, quad = lane >> 4;
  const int wr = (w >> 1) * 64, wc = (w & 1) * 64;
#pragma unroll
  for (int fr = 0; fr < 4; fr++)
#pragma unroll
    for (int fc = 0; fc < 4; fc++)
#pragma unroll
      for (int r = 0; r < 4; r++) {
        int m = rowBase + wr + fr * 16 + quad * 4 + r;
        int n = colBase + wc + fc * 16 + lm;
        out[(size_t)m * DIM + n] = acc[fr][fc][r];
      }
}

// --------------------------------------------- RMSNorm + RoPE (in place on q,k)
__global__ __launch_bounds__(256) void norm_rope(bf16* __restrict__ Q,
                                                 bf16* __restrict__ K,
                                                 const float* __restrict__ rope,
                                                 const float* __restrict__ qw,
                                                 const float* __restrict__ kw) {
  const int t = threadIdx.x, w = t >> 6, lane = t & 63;
  const int rid = blockIdx.x * 4 + w;
  const int which = rid >> 16;          // 0 = q, 1 = k
  const int row = rid & 65535;          // (b*16+h)*2048 + s
  bf16* ptr = (which ? K : Q) + (size_t)row * HEAD_DIM;
  const float* nw = which ? kw : qw;
  const int s = row & (SEQ - 1);

  float x0 = (float)ptr[lane];
  float x1 = (float)ptr[lane + 64];
  float ss = x0 * x0 + x1 * x1;
#pragma unroll
  for (int off = 32; off; off >>= 1) ss += __shfl_xor(ss, off);
  float r = rsqrtf(ss * (1.f / 128.f) + 1e-6f);
  float x0n = x0 * r * nw[lane];
  float x1n = x1 * r * nw[lane + 64];
  float4 f = ((const float4*)rope)[s * 64 + lane];
  float y0 = f.x * x0n + f.y * x1n;
  float y1 = f.z * x0n + f.w * x1n;
  if (!which) { y0 *= SM_SCALE; y1 *= SM_SCALE; }
  ptr[lane] = f2b(y0);
  ptr[lane + 64] = f2b(y1);
}

// --------------------------------------------------------- flash attention v4
// grid (bh=32, qt=16): bh fastest-varying -> bh%8 pins all 16 q-tile blocks of a
// (b,h) to one XCD; 4 bh * (K+V = 1 MB) = 4 MB = L2 -> staging is L2-hit.
// Block 256 = 4 waves: wave = (qh = w>>1, kb = w&1); Br=128 (2 reg q-sets of 32),
// Bc=64 with 32-row k-band per wave. K/V double-buffered in LDS via DMA issued
// one full compute-phase ahead. P's C->A layout transform done IN-REGISTER via
// 4x shfl_xor(32) per q-set (no LDS round trip).
__global__ __launch_bounds__(256, 2) void attn_kernel(const bf16* __restrict__ Q,
                                                      const bf16* __restrict__ K,
                                                      const bf16* __restrict__ VT,
                                                      bf16* __restrict__ O) {
  __shared__ __align__(16) bf16 Ks[2][64 * 128];   // [buf][kr][chunk ^ (kr&15)]
  __shared__ __align__(16) bf16 Vs[2][128 * 64];   // [buf][d][chunk ^ (d&7)]

  const int t = threadIdx.x, w = t >> 6, lane = t & 63;
  const int lq = lane & 31, h = lane >> 5;
  const int qh = w >> 1, kb = w & 1;
  const int bh = blockIdx.x, qt = blockIdx.y;

  // hoisted Q B-frags, 2 q-sets of 32 rows
  bf16x8 qf[2][8];
#pragma unroll
  for (int qs = 0; qs < 2; qs++) {
    const bf16* Qp = Q + ((size_t)bh * SEQ + qt * 128 + qh * 64 + qs * 32 + lq) * HEAD_DIM;
#pragma unroll
    for (int ks = 0; ks < 8; ks++)
      qf[qs][ks] = *(const bf16x8*)(Qp + ks * 16 + h * 8);
  }

  f32x16 oacc[2][4];
#pragma unroll
  for (int qs = 0; qs < 2; qs++)
#pragma unroll
    for (int nb = 0; nb < 4; nb++)
#pragma unroll
      for (int e = 0; e < 16; e++) oacc[qs][nb][e] = 0.f;
  float rsum[2] = {0.f, 0.f};

  const bf16* kbase = K + (size_t)bh * SEQ * HEAD_DIM;
  const bf16* vbase = VT + (size_t)bh * HEAD_DIM * SEQ;
  const int kr = kb * 32 + lq;

  // DMA-stage tile j into buffer bufi (source-address XOR swizzle, dest contiguous)
  auto stage = [&](int j, int bufi) {
    const bf16* kp = kbase + (size_t)j * 64 * HEAD_DIM;
    const bf16* vp = vbase + j * 64;
#pragma unroll
    for (int i = 0; i < 4; i++) {
      int c = i * 256 + t;
      int r = c >> 4, cc = c & 15;
      async16(kp + r * 128 + ((cc ^ (r & 15)) << 3), &Ks[bufi][(i * 256 + w * 64) * 8]);
    }
#pragma unroll
    for (int i = 0; i < 4; i++) {
      int c = i * 256 + t;
      int d = c >> 3, cc = c & 7;
      async16(vp + (size_t)d * SEQ + ((cc ^ (d & 7)) << 3), &Vs[bufi][(i * 256 + w * 64) * 8]);
    }
  };

  stage(0, 0);
  asm volatile("s_waitcnt vmcnt(0)" ::: "memory");
  __syncthreads();

  for (int j = 0; j < SEQ / 64; j++) {
    const int cur = j & 1;
    if (j + 1 < SEQ / 64) stage(j + 1, cur ^ 1);   // prefetch next tile

    // S^T = K Q^T on this wave's 32-row K-band; each kf feeds both q-sets
    f32x16 sacc[2];
#pragma unroll
    for (int qs = 0; qs < 2; qs++)
#pragma unroll
      for (int e = 0; e < 16; e++) sacc[qs][e] = -SMAX;  // bias so p = exp(sacc)
#pragma unroll
    for (int ks = 0; ks < 8; ks++) {
      int c = ks * 2 + h;
      bf16x8 kf = *(const bf16x8*)&Ks[cur][kr * 128 + ((c ^ (kr & 15)) << 3)];
      sacc[0] = __builtin_amdgcn_mfma_f32_32x32x16_bf16(kf, qf[0][ks], sacc[0], 0, 0, 0);
      sacc[1] = __builtin_amdgcn_mfma_f32_32x32x16_bf16(kf, qf[1][ks], sacc[1], 0, 0, 0);
    }

    // exp + pack + in-register C->A transform (cross-half shfl_xor)
    // C-layout: lane(q=lq,h) reg r holds k=(r&3)+8*(r>>2)+4h. A-frag wants k=8h+j.
    uint32_t a1[2][4], a2[2][4];
#pragma unroll
    for (int qs = 0; qs < 2; qs++) {
      float e[16];
#pragma unroll
      for (int r = 0; r < 16; r++) {
        e[r] = __expf(sacc[qs][r]);
        rsum[qs] += e[r];
      }
      uint32_t pk[8];
#pragma unroll
      for (int i = 0; i < 8; i++) pk[i] = pack2(e[2 * i], e[2 * i + 1]);
      uint32_t ta = h ? pk[0] : pk[2], tb = h ? pk[1] : pk[3];
      uint32_t tc = h ? pk[4] : pk[6], td = h ? pk[5] : pk[7];
      uint32_t ra = __shfl_xor((int)ta, 32), rb = __shfl_xor((int)tb, 32);
      uint32_t rc = __shfl_xor((int)tc, 32), rd = __shfl_xor((int)td, 32);
      a1[qs][0] = h ? ra : pk[0]; a1[qs][1] = h ? rb : pk[1];
      a1[qs][2] = h ? pk[2] : ra; a1[qs][3] = h ? pk[3] : rb;
      a2[qs][0] = h ? rc : pk[4]; a2[qs][1] = h ? rd : pk[5];
      a2[qs][2] = h ? pk[6] : rc; a2[qs][3] = h ? pk[7] : rd;
    }

    // O += P V on this wave's K-band; each bv feeds both q-sets
#pragma unroll
    for (int ks2 = 0; ks2 < 2; ks2++) {
      union { uint32_t u[4]; bf16x8 v; } ap0, ap1;
#pragma unroll
      for (int i = 0; i < 4; i++) {
        ap0.u[i] = ks2 ? a2[0][i] : a1[0][i];
        ap1.u[i] = ks2 ? a2[1][i] : a1[1][i];
      }
      int c2 = kb * 4 + ks2 * 2 + h;
#pragma unroll
      for (int nb = 0; nb < 4; nb++) {
        int rv = nb * 32 + lq;
        bf16x8 bv = *(const bf16x8*)&Vs[cur][rv * 64 + ((c2 ^ (rv & 7)) << 3)];
        oacc[0][nb] = __builtin_amdgcn_mfma_f32_32x32x16_bf16(ap0.v, bv, oacc[0][nb], 0, 0, 0);
        oacc[1][nb] = __builtin_amdgcn_mfma_f32_32x32x16_bf16(ap1.v, bv, oacc[1][nb], 0, 0, 0);
      }
    }

    asm volatile("s_waitcnt vmcnt(0)" ::: "memory");  // next tile's DMA (issued ~full iter ago)
    __syncthreads();
  }

  // ---- epilogue: merge kb pairs via LDS (alias Ks/Vs), normalize, store
  rsum[0] += __shfl_xor(rsum[0], 32);
  rsum[1] += __shfl_xor(rsum[1], 32);
  float* Om = (float*)&Ks[0][0];   // [pair][64 q][32 d] f32 = 16 KB
  float* Rs = (float*)&Vs[0][0];   // [pair][qs][32] f32
  const int pair = qh;
  const int b = bh >> 4, hh = bh & 15;
  float inv[2] = {0.f, 0.f};

#pragma unroll
  for (int nb = 0; nb < 4; nb++) {
    if (kb == 1) {
      if (nb == 0 && h == 0) {
        Rs[(pair * 2 + 0) * 32 + lq] = rsum[0];
        Rs[(pair * 2 + 1) * 32 + lq] = rsum[1];
      }
#pragma unroll
      for (int qs = 0; qs < 2; qs++)
#pragma unroll
        for (int r = 0; r < 16; r++) {
          int rowm = (r & 3) + 8 * (r >> 2) + 4 * h;
          Om[(pair * 64 + qs * 32 + rowm) * 32 + lq] = oacc[qs][nb][r];
        }
    }
    __syncthreads();
    if (kb == 0) {
      if (nb == 0) {
        inv[0] = 1.f / (rsum[0] + Rs[(pair * 2 + 0) * 32 + lq]);
        inv[1] = 1.f / (rsum[1] + Rs[(pair * 2 + 1) * 32 + lq]);
      }
#pragma unroll
      for (int qs = 0; qs < 2; qs++)
#pragma unroll
        for (int r = 0; r < 16; r++) {
          int rowm = (r & 3) + 8 * (r >> 2) + 4 * h;
          float val = oacc[qs][nb][r] + Om[(pair * 64 + qs * 32 + rowm) * 32 + lq];
          float iv = __shfl(inv[qs], rowm);
          int qg = qt * 128 + qh * 64 + qs * 32 + rowm;
          O[((size_t)b * SEQ + qg) * DIM + hh * HEAD_DIM + nb * 32 + lq] = f2b(val * iv);
        }
    }
    __syncthreads();
  }
}

extern "C" void kernel_launch(void* const* d_in, const int* in_sizes, int n_in,
                              void* d_out, int out_size, void* d_ws, size_t ws_size,
                              hipStream_t stream) {
  const float* x    = (const float*)d_in[0];
  const float* rope = (const float*)d_in[1];
  const float* Wq   = (const float*)d_in[2];
  const float* Wk   = (const float*)d_in[3];
  const float* Wv   = (const float*)d_in[4];
  const float* Wo   = (const float*)d_in[5];
  const float* qw   = (const float*)d_in[6];
  const float* kw   = (const float*)d_in[7];
  float* out = (float*)d_out;

  char* ws = (char*)d_ws;
  bf16* xb   = (bf16*)ws;                        // 16 MB; reused as attn-out
  bf16* wqkv = (bf16*)(ws + (16u << 20));        // 24 MB
  bf16* wo   = (bf16*)(ws + (40u << 20));        // 8 MB
  bf16* qb   = (bf16*)(ws + (48u << 20));        // 16 MB [B,H,S,Dh]
  bf16* kb   = (bf16*)(ws + (64u << 20));        // 16 MB [B,H,S,Dh]
  bf16* vt   = (bf16*)(ws + (80u << 20));        // 16 MB [B,H,Dh,S]
  bf16* attn = xb;

  const int NX = MROWS * DIM;
  const int NW = DIM * DIM;

  cvt_kernel<<<NX / 8 / 256, 256, 0, stream>>>(x, xb, NX);
  cvt_w4<<<4 * (NW / 8 / 256), 256, 0, stream>>>(Wq, Wk, Wv, Wo, wqkv, wo);

  gemm_qkv<<<dim3(NQKV / 128, MROWS / 128), 256, 0, stream>>>(xb, wqkv, qb, kb, vt);
  norm_rope<<<(2 * BATCH * N_HEADS * SEQ) / 4, 256, 0, stream>>>(qb, kb, rope, qw, kw);
  attn_kernel<<<dim3(BATCH * N_HEADS, SEQ / 128), 256, 0, stream>>>(qb, kb, vt, attn);
  gemm_out<<<dim3(DIM / 128, MROWS / 128), 256, 0, stream>>>(attn, wo, out);
}

// Round 5
// 456.219 us; speedup vs baseline: 1.2679x; 1.0886x over previous
//
#include <hip/hip_runtime.h>
#include <hip/hip_bf16.h>
#include <stdint.h>

typedef __bf16 bf16;
typedef __bf16 bf16x4 __attribute__((ext_vector_type(4)));
typedef __bf16 bf16x8 __attribute__((ext_vector_type(8)));
typedef float f32x4 __attribute__((ext_vector_type(4)));
typedef float f32x16 __attribute__((ext_vector_type(16)));

#define N_HEADS 16
#define HEAD_DIM 128
#define SEQ 2048
#define DIM 2048
#define BATCH 2
#define MROWS (BATCH * SEQ)          // 4096
#define NQKV (3 * DIM)               // 6144
#define SM_SCALE 0.08838834764831845f  // 1/sqrt(128)
#define SMAX 24.0f                     // static softmax max

__device__ __forceinline__ bf16 f2b(float f) {
  union { __hip_bfloat16 h; bf16 b; } u;
  u.h = __float2bfloat16(f);
  return u.b;
}

__device__ __forceinline__ uint32_t pack2(float a, float b) {
  union { __hip_bfloat16 h; unsigned short s; } ua, ub;
  ua.h = __float2bfloat16(a); ub.h = __float2bfloat16(b);
  return (uint32_t)ua.s | ((uint32_t)ub.s << 16);   // a in low 16 (even k)
}

// async global->LDS (GEMMs only; lane-contiguous source, the m97 pattern)
__device__ __forceinline__ void async16(const bf16* g, bf16* l) {
  __builtin_amdgcn_global_load_lds(
      (__attribute__((address_space(1))) void*)(uintptr_t)g,
      (__attribute__((address_space(3))) void*)(uintptr_t)l,
      16, 0, 0);
}

// ---------------------------------------------------------------- cvt f32->bf16
__global__ __launch_bounds__(256) void cvt_kernel(const float* __restrict__ src,
                                                  bf16* __restrict__ dst, int n) {
  int i = (blockIdx.x * 256 + threadIdx.x) * 8;
  if (i >= n) return;
  float4 a = *(const float4*)(src + i);
  float4 b = *(const float4*)(src + i + 4);
  bf16x8 o;
  o[0] = f2b(a.x); o[1] = f2b(a.y); o[2] = f2b(a.z); o[3] = f2b(a.w);
  o[4] = f2b(b.x); o[5] = f2b(b.y); o[6] = f2b(b.z); o[7] = f2b(b.w);
  *(bf16x8*)(dst + i) = o;
}

// fused cvt of the 4 weight matrices; w0..w2 -> wqkv, w3 -> wo
__global__ __launch_bounds__(256) void cvt_w4(const float* __restrict__ w0,
                                              const float* __restrict__ w1,
                                              const float* __restrict__ w2,
                                              const float* __restrict__ w3,
                                              bf16* __restrict__ wqkv,
                                              bf16* __restrict__ wo) {
  const int per = (DIM * DIM) / 8 / 256;
  int which = blockIdx.x / per;
  int i = (blockIdx.x % per) * 256 * 8 + threadIdx.x * 8;
  const float* src = which == 0 ? w0 : which == 1 ? w1 : which == 2 ? w2 : w3;
  bf16* dst = which < 3 ? wqkv + (size_t)which * DIM * DIM : wo;
  float4 a = *(const float4*)(src + i);
  float4 b = *(const float4*)(src + i + 4);
  bf16x8 o;
  o[0] = f2b(a.x); o[1] = f2b(a.y); o[2] = f2b(a.z); o[3] = f2b(a.w);
  o[4] = f2b(b.x); o[5] = f2b(b.y); o[6] = f2b(b.z); o[7] = f2b(b.w);
  *(bf16x8*)(dst + i) = o;
}

// ------------------------------------------------- m97-style 128x128x32 mainloop
__device__ __forceinline__ void gemm_tile_mainloop(
    const bf16* __restrict__ A, const bf16* __restrict__ Bw, int K,
    int rowBase, int colBase, bf16* lA, bf16* lB, f32x4 acc[4][4]) {
  const int t = threadIdx.x;
  const int w = t >> 6, lane = t & 63;
  const int lm = lane & 15, quad = lane >> 4;
  const int wr = (w >> 1) * 64, wc = (w & 1) * 64;

  for (int kt = 0; kt < K; kt += 32) {
#pragma unroll
    for (int i = 0; i < 2; i++) {
      const int c = i * 256 + t;
      const int r = c >> 2, cc = (c & 3) << 3;
      async16(A + (size_t)(rowBase + r) * K + (kt + cc), lA + (i * 256 + w * 64) * 8);
      async16(Bw + (size_t)(colBase + r) * K + (kt + cc), lB + (i * 256 + w * 64) * 8);
    }
    asm volatile("s_waitcnt vmcnt(0)" ::: "memory");
    __syncthreads();
    bf16x8 af[4], bfr[4];
#pragma unroll
    for (int f = 0; f < 4; f++)
      af[f] = *(const bf16x8*)(lA + (wr + f * 16 + lm) * 32 + quad * 8);
#pragma unroll
    for (int f = 0; f < 4; f++)
      bfr[f] = *(const bf16x8*)(lB + (wc + f * 16 + lm) * 32 + quad * 8);
#pragma unroll
    for (int fr = 0; fr < 4; fr++)
#pragma unroll
      for (int fc = 0; fc < 4; fc++)
        acc[fr][fc] = __builtin_amdgcn_mfma_f32_16x16x32_bf16(af[fr], bfr[fc], acc[fr][fc], 0, 0, 0);
    __syncthreads();
  }
}

// QKV projection: Q,K -> [B,H,S,Dh]; V -> TRANSPOSED [B,H,Dh,S]
__global__ __launch_bounds__(256) void gemm_qkv(const bf16* __restrict__ X,
                                                const bf16* __restrict__ W,
                                                bf16* __restrict__ Q,
                                                bf16* __restrict__ Kv,
                                                bf16* __restrict__ VT) {
  __shared__ __align__(16) bf16 lA[128 * 32];
  __shared__ __align__(16) bf16 lB[128 * 32];
  f32x4 acc[4][4];
  f32x4 z = {0.f, 0.f, 0.f, 0.f};
#pragma unroll
  for (int i = 0; i < 4; i++)
#pragma unroll
    for (int j = 0; j < 4; j++) acc[i][j] = z;

  const int rowBase = blockIdx.y * 128, colBase = blockIdx.x * 128;
  gemm_tile_mainloop(X, W, DIM, rowBase, colBase, lA, lB, acc);

  const int t = threadIdx.x, w = t >> 6, lane = t & 63;
  const int lm = lane & 15, quad = lane >> 4;
  const int wr = (w >> 1) * 64, wc = (w & 1) * 64;
  const int which = colBase >> 11;  // 0=Q 1=K 2=V
  if (which < 2) {
    bf16* dst = which ? Kv : Q;
#pragma unroll
    for (int fr = 0; fr < 4; fr++)
#pragma unroll
      for (int fc = 0; fc < 4; fc++)
#pragma unroll
        for (int r = 0; r < 4; r++) {
          int m = rowBase + wr + fr * 16 + quad * 4 + r;
          int n = (colBase + wc + fc * 16 + lm) & 2047;
          int h = n >> 7, d = n & 127;
          int b = m >> 11, s = m & 2047;
          dst[(((size_t)(b * N_HEADS + h) * SEQ) + s) * HEAD_DIM + d] = f2b(acc[fr][fc][r]);
        }
  } else {
#pragma unroll
    for (int fr = 0; fr < 4; fr++)
#pragma unroll
      for (int fc = 0; fc < 4; fc++) {
        int n = (colBase + wc + fc * 16 + lm) & 2047;
        int h = n >> 7, d = n & 127;
        int m = rowBase + wr + fr * 16 + quad * 4;
        int b = m >> 11, s = m & 2047;
        bf16x4 pk;
#pragma unroll
        for (int r = 0; r < 4; r++) pk[r] = f2b(acc[fr][fc][r]);
        *(bf16x4*)&VT[((size_t)(b * N_HEADS + h) * HEAD_DIM + d) * SEQ + s] = pk;
      }
  }
}

// Output projection
__global__ __launch_bounds__(256) void gemm_out(const bf16* __restrict__ A,
                                                const bf16* __restrict__ W,
                                                float* __restrict__ out) {
  __shared__ __align__(16) bf16 lA[128 * 32];
  __shared__ __align__(16) bf16 lB[128 * 32];
  f32x4 acc[4][4];
  f32x4 z = {0.f, 0.f, 0.f, 0.f};
#pragma unroll
  for (int i = 0; i < 4; i++)
#pragma unroll
    for (int j = 0; j < 4; j++) acc[i][j] = z;

  const int rowBase = blockIdx.y * 128, colBase = blockIdx.x * 128;
  gemm_tile_mainloop(A, W, DIM, rowBase, colBase, lA, lB, acc);

  const int t = threadIdx.x, w = t >> 6, lane = t & 63;
  const int lm = lane & 15, quad = lane >> 4;
  const int wr = (w >> 1) * 64, wc = (w & 1) * 64;
#pragma unroll
  for (int fr = 0; fr < 4; fr++)
#pragma unroll
    for (int fc = 0; fc < 4; fc++)
#pragma unroll
      for (int r = 0; r < 4; r++) {
        int m = rowBase + wr + fr * 16 + quad * 4 + r;
        int n = colBase + wc + fc * 16 + lm;
        out[(size_t)m * DIM + n] = acc[fr][fc][r];
      }
}

// --------------------------------------------- RMSNorm + RoPE (in place on q,k)
__global__ __launch_bounds__(256) void norm_rope(bf16* __restrict__ Q,
                                                 bf16* __restrict__ K,
                                                 const float* __restrict__ rope,
                                                 const float* __restrict__ qw,
                                                 const float* __restrict__ kw) {
  const int t = threadIdx.x, w = t >> 6, lane = t & 63;
  const int rid = blockIdx.x * 4 + w;
  const int which = rid >> 16;          // 0 = q, 1 = k
  const int row = rid & 65535;          // (b*16+h)*2048 + s
  bf16* ptr = (which ? K : Q) + (size_t)row * HEAD_DIM;
  const float* nw = which ? kw : qw;
  const int s = row & (SEQ - 1);

  float x0 = (float)ptr[lane];
  float x1 = (float)ptr[lane + 64];
  float ss = x0 * x0 + x1 * x1;
#pragma unroll
  for (int off = 32; off; off >>= 1) ss += __shfl_xor(ss, off);
  float r = rsqrtf(ss * (1.f / 128.f) + 1e-6f);
  float x0n = x0 * r * nw[lane];
  float x1n = x1 * r * nw[lane + 64];
  float4 f = ((const float4*)rope)[s * 64 + lane];
  float y0 = f.x * x0n + f.y * x1n;
  float y1 = f.z * x0n + f.w * x1n;
  if (!which) { y0 *= SM_SCALE; y1 *= SM_SCALE; }
  ptr[lane] = f2b(y0);
  ptr[lane + 64] = f2b(y1);
}

// --------------------------------------------------------- flash attention v5
// grid (bh=32, qt=16): bh%8 pins all q-tile blocks of a (b,h) to one XCD (L2
// capture of K+V — verified R4: FETCH 317->57 MB). Block 256 = 4 waves:
// wave = (qh = w>>1, kb = w&1); Br=128 (2 reg q-sets of 32), Bc=64, 32-row
// k-band per wave. Staging = coalesced global b128 -> VGPR (issued one full
// compute phase ahead; compiler emits fine-grained vmcnt at first use) ->
// swizzled ds_write. NO global_load_lds here: R3/R4 showed swizzled-source DMA
// doesn't coalesce and the compiler drains the DMA queue before any ds_read.
// P's C->A transform in-register via shfl_xor(32). Static-max softmax.
__global__ __launch_bounds__(256, 2) void attn_kernel(const bf16* __restrict__ Q,
                                                      const bf16* __restrict__ K,
                                                      const bf16* __restrict__ VT,
                                                      bf16* __restrict__ O) {
  __shared__ __align__(16) bf16 Ks[64 * 128];   // [kr][chunk ^ (kr&15)]
  __shared__ __align__(16) bf16 Vs[128 * 64];   // [d][chunk ^ (d&7)]

  const int t = threadIdx.x, w = t >> 6, lane = t & 63;
  const int lq = lane & 31, h = lane >> 5;
  const int qh = w >> 1, kb = w & 1;
  const int bh = blockIdx.x, qt = blockIdx.y;

  // hoisted Q B-frags, 2 q-sets of 32 rows
  bf16x8 qf[2][8];
#pragma unroll
  for (int qs = 0; qs < 2; qs++) {
    const bf16* Qp = Q + ((size_t)bh * SEQ + qt * 128 + qh * 64 + qs * 32 + lq) * HEAD_DIM;
#pragma unroll
    for (int ks = 0; ks < 8; ks++)
      qf[qs][ks] = *(const bf16x8*)(Qp + ks * 16 + h * 8);
  }

  f32x16 oacc[2][4];
#pragma unroll
  for (int qs = 0; qs < 2; qs++)
#pragma unroll
    for (int nb = 0; nb < 4; nb++)
#pragma unroll
      for (int e = 0; e < 16; e++) oacc[qs][nb][e] = 0.f;
  float rsum[2] = {0.f, 0.f};

  const bf16* kbase = K + (size_t)bh * SEQ * HEAD_DIM;
  const bf16* vbase = VT + (size_t)bh * HEAD_DIM * SEQ;
  const int kr = kb * 32 + lq;

  // staging registers + index helpers (per wave: 16 K-rows, 32 V-rows)
  const int krow = w * 16 + (lane >> 4), kcc = lane & 15;        // K: 4 rows/instr
  const int vrow = w * 32 + (lane >> 3), vcc = lane & 7;         // V: 8 rows/instr
  bf16x8 kreg[4], vreg[4];

  auto load_tile = [&](int j) {
    const bf16* kp = kbase + (size_t)j * 64 * HEAD_DIM;
    const bf16* vp = vbase + j * 64;
#pragma unroll
    for (int i = 0; i < 4; i++)
      kreg[i] = *(const bf16x8*)(kp + (krow + i * 4) * HEAD_DIM + kcc * 8);
#pragma unroll
    for (int i = 0; i < 4; i++)
      vreg[i] = *(const bf16x8*)(vp + (size_t)(vrow + i * 8) * SEQ + vcc * 8);
  };

  load_tile(0);

  for (int j = 0; j < SEQ / 64; j++) {
    // phase A: write staged regs (tile j) into swizzled LDS
#pragma unroll
    for (int i = 0; i < 4; i++) {
      int r = krow + i * 4;
      *(bf16x8*)&Ks[r * 128 + ((kcc ^ (r & 15)) << 3)] = kreg[i];
    }
#pragma unroll
    for (int i = 0; i < 4; i++) {
      int d = vrow + i * 8;
      *(bf16x8*)&Vs[d * 64 + ((vcc ^ (d & 7)) << 3)] = vreg[i];
    }
    __syncthreads();

    // phase B: issue next tile's global loads, then compute on LDS tile j
    if (j + 1 < SEQ / 64) load_tile(j + 1);

    // S^T = K Q^T on this wave's 32-row K-band; each kf feeds both q-sets
    f32x16 sacc[2];
#pragma unroll
    for (int qs = 0; qs < 2; qs++)
#pragma unroll
      for (int e = 0; e < 16; e++) sacc[qs][e] = -SMAX;  // bias so p = exp(sacc)
#pragma unroll
    for (int ks = 0; ks < 8; ks++) {
      int c = ks * 2 + h;
      bf16x8 kf = *(const bf16x8*)&Ks[kr * 128 + ((c ^ (kr & 15)) << 3)];
      sacc[0] = __builtin_amdgcn_mfma_f32_32x32x16_bf16(kf, qf[0][ks], sacc[0], 0, 0, 0);
      sacc[1] = __builtin_amdgcn_mfma_f32_32x32x16_bf16(kf, qf[1][ks], sacc[1], 0, 0, 0);
    }

    // exp + pack + in-register C->A transform (cross-half shfl_xor)
    uint32_t a1[2][4], a2[2][4];
#pragma unroll
    for (int qs = 0; qs < 2; qs++) {
      float e[16];
#pragma unroll
      for (int r = 0; r < 16; r++) {
        e[r] = __expf(sacc[qs][r]);
        rsum[qs] += e[r];
      }
      uint32_t pk[8];
#pragma unroll
      for (int i = 0; i < 8; i++) pk[i] = pack2(e[2 * i], e[2 * i + 1]);
      uint32_t ta = h ? pk[0] : pk[2], tb = h ? pk[1] : pk[3];
      uint32_t tc = h ? pk[4] : pk[6], td = h ? pk[5] : pk[7];
      uint32_t ra = __shfl_xor((int)ta, 32), rb = __shfl_xor((int)tb, 32);
      uint32_t rc = __shfl_xor((int)tc, 32), rd = __shfl_xor((int)td, 32);
      a1[qs][0] = h ? ra : pk[0]; a1[qs][1] = h ? rb : pk[1];
      a1[qs][2] = h ? pk[2] : ra; a1[qs][3] = h ? pk[3] : rb;
      a2[qs][0] = h ? rc : pk[4]; a2[qs][1] = h ? rd : pk[5];
      a2[qs][2] = h ? pk[6] : rc; a2[qs][3] = h ? pk[7] : rd;
    }

    // O += P V on this wave's K-band; each bv feeds both q-sets
#pragma unroll
    for (int ks2 = 0; ks2 < 2; ks2++) {
      union { uint32_t u[4]; bf16x8 v; } ap0, ap1;
#pragma unroll
      for (int i = 0; i < 4; i++) {
        ap0.u[i] = ks2 ? a2[0][i] : a1[0][i];
        ap1.u[i] = ks2 ? a2[1][i] : a1[1][i];
      }
      int c2 = kb * 4 + ks2 * 2 + h;
#pragma unroll
      for (int nb = 0; nb < 4; nb++) {
        int rv = nb * 32 + lq;
        bf16x8 bv = *(const bf16x8*)&Vs[rv * 64 + ((c2 ^ (rv & 7)) << 3)];
        oacc[0][nb] = __builtin_amdgcn_mfma_f32_32x32x16_bf16(ap0.v, bv, oacc[0][nb], 0, 0, 0);
        oacc[1][nb] = __builtin_amdgcn_mfma_f32_32x32x16_bf16(ap1.v, bv, oacc[1][nb], 0, 0, 0);
      }
    }
    __syncthreads();   // all waves done reading LDS tile j before next ds_write
  }

  // ---- epilogue: merge kb pairs via LDS (alias Ks/Vs), normalize, store
  rsum[0] += __shfl_xor(rsum[0], 32);
  rsum[1] += __shfl_xor(rsum[1], 32);
  float* Om = (float*)&Ks[0];   // [pair][64 q][32 d] f32 = 16 KB
  float* Rs = (float*)&Vs[0];   // [pair][qs][32] f32
  const int pair = qh;
  const int b = bh >> 4, hh = bh & 15;
  float inv[2] = {0.f, 0.f};

#pragma unroll
  for (int nb = 0; nb < 4; nb++) {
    if (kb == 1) {
      if (nb == 0 && h == 0) {
        Rs[(pair * 2 + 0) * 32 + lq] = rsum[0];
        Rs[(pair * 2 + 1) * 32 + lq] = rsum[1];
      }
#pragma unroll
      for (int qs = 0; qs < 2; qs++)
#pragma unroll
        for (int r = 0; r < 16; r++) {
          int rowm = (r & 3) + 8 * (r >> 2) + 4 * h;
          Om[(pair * 64 + qs * 32 + rowm) * 32 + lq] = oacc[qs][nb][r];
        }
    }
    __syncthreads();
    if (kb == 0) {
      if (nb == 0) {
        inv[0] = 1.f / (rsum[0] + Rs[(pair * 2 + 0) * 32 + lq]);
        inv[1] = 1.f / (rsum[1] + Rs[(pair * 2 + 1) * 32 + lq]);
      }
#pragma unroll
      for (int qs = 0; qs < 2; qs++)
#pragma unroll
        for (int r = 0; r < 16; r++) {
          int rowm = (r & 3) + 8 * (r >> 2) + 4 * h;
          float val = oacc[qs][nb][r] + Om[(pair * 64 + qs * 32 + rowm) * 32 + lq];
          float iv = __shfl(inv[qs], rowm);
          int qg = qt * 128 + qh * 64 + qs * 32 + rowm;
          O[((size_t)b * SEQ + qg) * DIM + hh * HEAD_DIM + nb * 32 + lq] = f2b(val * iv);
        }
    }
    __syncthreads();
  }
}

extern "C" void kernel_launch(void* const* d_in, const int* in_sizes, int n_in,
                              void* d_out, int out_size, void* d_ws, size_t ws_size,
                              hipStream_t stream) {
  const float* x    = (const float*)d_in[0];
  const float* rope = (const float*)d_in[1];
  const float* Wq   = (const float*)d_in[2];
  const float* Wk   = (const float*)d_in[3];
  const float* Wv   = (const float*)d_in[4];
  const float* Wo   = (const float*)d_in[5];
  const float* qw   = (const float*)d_in[6];
  const float* kw   = (const float*)d_in[7];
  float* out = (float*)d_out;

  char* ws = (char*)d_ws;
  bf16* xb   = (bf16*)ws;                        // 16 MB; reused as attn-out
  bf16* wqkv = (bf16*)(ws + (16u << 20));        // 24 MB
  bf16* wo   = (bf16*)(ws + (40u << 20));        // 8 MB
  bf16* qb   = (bf16*)(ws + (48u << 20));        // 16 MB [B,H,S,Dh]
  bf16* kb   = (bf16*)(ws + (64u << 20));        // 16 MB [B,H,S,Dh]
  bf16* vt   = (bf16*)(ws + (80u << 20));        // 16 MB [B,H,Dh,S]
  bf16* attn = xb;

  const int NX = MROWS * DIM;
  const int NW = DIM * DIM;

  cvt_kernel<<<NX / 8 / 256, 256, 0, stream>>>(x, xb, NX);
  cvt_w4<<<4 * (NW / 8 / 256), 256, 0, stream>>>(Wq, Wk, Wv, Wo, wqkv, wo);

  gemm_qkv<<<dim3(NQKV / 128, MROWS / 128), 256, 0, stream>>>(xb, wqkv, qb, kb, vt);
  norm_rope<<<(2 * BATCH * N_HEADS * SEQ) / 4, 256, 0, stream>>>(qb, kb, rope, qw, kw);
  attn_kernel<<<dim3(BATCH * N_HEADS, SEQ / 128), 256, 0, stream>>>(qb, kb, vt, attn);
  gemm_out<<<dim3(DIM / 128, MROWS / 128), 256, 0, stream>>>(attn, wo, out);
}